// Round 1
// 647.421 us; speedup vs baseline: 1.3859x; 1.3859x over previous
//
#include <hip/hip_runtime.h>
#include <stdint.h>

#define B_ 4
#define H_ 640
#define W_ 640
#define C_ 64
#define K_ 2048
#define N_ (H_ * W_)
#define NBINS 131072        // 2^17 bins of (bits >> 13)
#define CAP 4096            // candidate cap per batch (power of 2 for bitonic)
                            // expected candidates ~ 2048 + ~21 (boundary bin), huge margin
#define CBLK 64             // collect blocks per batch
#define CHUNK (N_ / CBLK)   // 6400 elements per collect block (25 per thread @256)

// ---- workspace layout (bytes) ----
#define OFF_BITS   0
#define SZ_BITS    (B_ * N_ * 4)                 // 6,553,600
#define OFF_HIST   (OFF_BITS + SZ_BITS)          // 6,553,600
#define SZ_HIST    (B_ * NBINS * 4)              // 2,097,152
#define OFF_CCNT   (OFF_HIST + SZ_HIST)          // 8,650,752
#define SZ_CCNT    256                           // 4 counters padded to 64B lines
#define OFF_BSTAR  (OFF_CCNT + SZ_CCNT)          // 8,651,008
#define SZ_BSTAR   16
#define OFF_CAND   (OFF_BSTAR + SZ_BSTAR)        // 8,651,024 (16B aligned)
#define SZ_CAND    (B_ * CAP * 8)                // 131,072
#define OFF_TOPK   (OFF_CAND + SZ_CAND)
#define SZ_TOPK    (B_ * K_ * 4)

// Kernel 1: 3x3 NMS (-inf pad semantics) + histogram of nonzero value bits
__global__ void nms_hist_kernel(const float* __restrict__ p,
                                uint32_t* __restrict__ bits_out,
                                uint32_t* __restrict__ hist) {
    int t = blockIdx.x * blockDim.x + threadIdx.x;
    if (t >= B_ * N_) return;
    int b = t / N_;
    int i = t - b * N_;
    int y = i / W_;
    int x = i - y * W_;
    const float* pb = p + (size_t)b * N_;
    float c = pb[i];
    float m = c;
    #pragma unroll
    for (int dy = -1; dy <= 1; dy++) {
        int yy = y + dy;
        if (yy < 0 || yy >= H_) continue;
        #pragma unroll
        for (int dx = -1; dx <= 1; dx++) {
            int xx = x + dx;
            if (xx < 0 || xx >= W_) continue;
            m = fmaxf(m, pb[yy * W_ + xx]);
        }
    }
    float nms = (c == m) ? c : 0.0f;
    uint32_t bits = __float_as_uint(nms);   // nms >= 0 -> monotone
    bits_out[t] = bits;
    if (bits) atomicAdd(&hist[b * NBINS + (bits >> 13)], 1u);
}

// Kernel 2: per-batch, find bin b* such that count(bins >= b*) >= K > count(bins > b*)
// Parallel: 1024 threads x 128 bins each -> LDS suffix scan -> wave-0 shfl suffix
// scan of the selected 128-bin segment. No serial dependent-load tails.
__global__ __launch_bounds__(1024) void findbin_kernel(const uint32_t* __restrict__ hist,
                                                       uint32_t* __restrict__ binstar) {
    int b = blockIdx.x;
    const uint32_t* h = hist + b * NBINS;
    __shared__ uint32_t suf[1024];
    __shared__ uint32_t ssel, scum;
    int tid = threadIdx.x;
    uint32_t s = 0;
    int base = tid * 128;
    for (int j = 0; j < 128; j++) s += h[base + j];
    suf[tid] = s;
    if (tid == 0) ssel = 0xFFFFFFFFu;
    __syncthreads();
    // inclusive suffix scan (Hillis-Steele), read-all-then-write-all per step
    for (int off = 1; off < 1024; off <<= 1) {
        uint32_t v = suf[tid];
        uint32_t add = (tid + off < 1024) ? suf[tid + off] : 0u;
        __syncthreads();
        suf[tid] = v + add;
        __syncthreads();
    }
    uint32_t inc = suf[tid];       // sum over segments >= tid
    uint32_t above = inc - s;      // sum over segments >  tid
    if (above < (uint32_t)K_ && inc >= (uint32_t)K_) { ssel = tid; scum = above; }
    __syncthreads();
    if (tid < 64) {
        uint32_t sel = ssel;
        if (sel != 0xFFFFFFFFu) {
            int b2 = sel * 128 + tid * 2;
            uint32_t c0 = h[b2], c1 = h[b2 + 1];
            uint32_t pair = c0 + c1;
            uint32_t acc = pair;            // inclusive lane-suffix sum of pair
            #pragma unroll
            for (int off = 1; off < 64; off <<= 1) {
                uint32_t v = __shfl_down(acc, off);
                if (tid + off < 64) acc += v;
            }
            uint32_t aboveL = scum + (acc - pair);   // sum over lanes > tid
            if (aboveL < (uint32_t)K_ && aboveL + pair >= (uint32_t)K_) {
                uint32_t bstar = (aboveL + c1 >= (uint32_t)K_) ? (uint32_t)(b2 + 1)
                                                               : (uint32_t)b2;
                binstar[b] = bstar;          // exactly one lane matches
            }
        } else if (tid == 0) {
            binstar[b] = 0;                  // fewer than K nonzero: take all
        }
    }
}

// Kernel 3: collect candidate keys (value bits desc, index asc tie-break).
// Two-phase block aggregation: ONE atomic per block (padded counters) instead of
// one per candidate -- kills the same-line atomic serialization chain.
__global__ __launch_bounds__(256) void collect_kernel(const uint32_t* __restrict__ bits_in,
                                                      const uint32_t* __restrict__ binstar,
                                                      uint32_t* __restrict__ ccnt,
                                                      unsigned long long* __restrict__ cand) {
    int b = blockIdx.x / CBLK;
    int c = blockIdx.x - b * CBLK;
    int base = b * N_ + c * CHUNK;
    uint32_t bstar = binstar[b];
    int tid = threadIdx.x;
    int lane = tid & 63, wv = tid >> 6;
    __shared__ uint32_t wtot[4];
    __shared__ uint32_t blkbase;

    // phase 1: count passers in this block's chunk
    uint32_t cnt = 0;
    for (int j = tid; j < CHUNK; j += 256) {
        uint32_t bits = bits_in[base + j];
        if (bits && (bits >> 13) >= bstar) cnt++;
    }
    #pragma unroll
    for (int off = 32; off > 0; off >>= 1) cnt += __shfl_down(cnt, off);
    if (lane == 0) wtot[wv] = cnt;
    __syncthreads();
    if (tid == 0) {
        uint32_t tot = wtot[0] + wtot[1] + wtot[2] + wtot[3];
        blkbase = tot ? atomicAdd(&ccnt[b * 16], tot) : 0u;
    }
    __syncthreads();
    uint32_t wbase = blkbase;
    #pragma unroll
    for (int w2 = 0; w2 < 4; w2++) if (w2 < wv) wbase += wtot[w2];

    // phase 2: deterministic intra-wave placement via ballot prefix
    uint32_t run = 0;
    for (int j = tid; j < CHUNK; j += 256) {   // CHUNK % 256 == 0: no ragged tail
        uint32_t bits = bits_in[base + j];
        bool pass = bits && (bits >> 13) >= bstar;
        unsigned long long mask = __ballot(pass);
        if (pass) {
            uint32_t pos = wbase + run + (uint32_t)__popcll(mask & ((1ull << lane) - 1));
            int i = c * CHUNK + j;
            if (pos < CAP)
                cand[(size_t)b * CAP + pos] =
                    ((unsigned long long)bits << 32) | (unsigned long long)(0xFFFFFFFFu - (uint32_t)i);
        }
        run += (uint32_t)__popcll(mask);
    }
}

// Kernel 4: per-batch bitonic sort (descending) of <= CAP keys, emit top-K indices
__global__ __launch_bounds__(1024) void sort_kernel(const unsigned long long* __restrict__ cand,
                                                    const uint32_t* __restrict__ ccnt,
                                                    uint32_t* __restrict__ topk) {
    __shared__ unsigned long long sh[CAP];   // 32 KB
    int b = blockIdx.x;
    int tid = threadIdx.x;
    uint32_t cnt = ccnt[b * 16];
    if (cnt > CAP) cnt = CAP;
    const unsigned long long* cb = cand + (size_t)b * CAP;
    for (int j = tid; j < CAP; j += 1024) sh[j] = (j < (int)cnt) ? cb[j] : 0ULL;
    __syncthreads();
    for (unsigned k = 2; k <= CAP; k <<= 1) {
        for (unsigned j = k >> 1; j > 0; j >>= 1) {
            for (unsigned t = tid; t < CAP / 2; t += 1024) {
                unsigned i = (t / j) * (2 * j) + (t % j);
                unsigned ixj = i + j;
                unsigned long long a = sh[i], cc = sh[ixj];
                bool dirDesc = ((i & k) == 0);
                if (dirDesc ? (a < cc) : (a > cc)) { sh[i] = cc; sh[ixj] = a; }
            }
            __syncthreads();
        }
    }
    for (int k2 = tid; k2 < K_; k2 += 1024) {
        topk[b * K_ + k2] = 0xFFFFFFFFu - (uint32_t)(sh[k2] & 0xFFFFFFFFull);
    }
}

// Kernel 5: one wave (64 lanes) per keypoint: subpixel softmax refine + bilinear sample
__global__ void final_kernel(const uint32_t* __restrict__ topk,
                             const float* __restrict__ probs,
                             const float* __restrict__ logits,
                             const float* __restrict__ fm,
                             float* __restrict__ out) {
    int gtid = blockIdx.x * blockDim.x + threadIdx.x;
    int wid = gtid >> 6;          // one wave per keypoint
    int lane = threadIdx.x & 63;
    if (wid >= B_ * K_) return;
    int b = wid / K_;
    int k = wid - b * K_;
    int idx = (int)topk[b * K_ + k];
    int h = idx / W_;
    int w = idx - h * W_;

    // 3x3 logit patch, zero-padded borders, temp 0.5 softmax
    const float* lg = logits + (size_t)b * N_;
    float v[9];
    #pragma unroll
    for (int di = 0; di < 3; di++) {
        #pragma unroll
        for (int dj = 0; dj < 3; dj++) {
            int yy = h + di - 1, xx = w + dj - 1;
            float val = (yy >= 0 && yy < H_ && xx >= 0 && xx < W_) ? lg[yy * W_ + xx] : 0.0f;
            v[di * 3 + dj] = val * 2.0f;   // / SUBPIXEL_TEMP
        }
    }
    float m = v[0];
    #pragma unroll
    for (int j = 1; j < 9; j++) m = fmaxf(m, v[j]);
    float e[9], s = 0.0f;
    #pragma unroll
    for (int j = 0; j < 9; j++) { e[j] = __expf(v[j] - m); s += e[j]; }
    float inv = 1.0f / s;
    float dx = 0.0f, dy = 0.0f;
    #pragma unroll
    for (int di = 0; di < 3; di++) {
        #pragma unroll
        for (int dj = 0; dj < 3; dj++) {
            float pr = e[di * 3 + dj] * inv;
            dx += pr * (float)(dj - 1);
            dy += pr * (float)(di - 1);
        }
    }
    float x = (float)w + dx;
    float y = (float)h + dy;

    // bilinear sample coords (clipped)
    float xc = fminf(fmaxf(x, 0.0f), (float)(W_ - 1));
    float yc = fminf(fmaxf(y, 0.0f), (float)(H_ - 1));
    float x0f = floorf(xc), y0f = floorf(yc);
    float wx = xc - x0f, wy = yc - y0f;
    int x0 = (int)x0f, y0 = (int)y0f;
    int x1 = min(x0 + 1, W_ - 1), y1 = min(y0 + 1, H_ - 1);
    float w00 = (1.0f - wx) * (1.0f - wy);
    float w01 = wx * (1.0f - wy);
    float w10 = (1.0f - wx) * wy;
    float w11 = wx * wy;
    int i00 = y0 * W_ + x0, i01 = y0 * W_ + x1, i10 = y1 * W_ + x0, i11 = y1 * W_ + x1;

    float* ob = out + ((size_t)b * K_ + k) * (C_ + 3);

    // lane l samples feature channel l
    const float* ch = fm + ((size_t)b * C_ + lane) * N_;
    float sv = ch[i00] * w00 + ch[i01] * w01 + ch[i10] * w10 + ch[i11] * w11;
    ob[3 + lane] = sv;

    if (lane == 0) {
        const float* pp = probs + (size_t)b * N_;
        float sp = pp[i00] * w00 + pp[i01] * w01 + pp[i10] * w10 + pp[i11] * w11;
        ob[0] = x;
        ob[1] = y;
        ob[2] = sp;
    }
}

extern "C" void kernel_launch(void* const* d_in, const int* in_sizes, int n_in,
                              void* d_out, int out_size, void* d_ws, size_t ws_size,
                              hipStream_t stream) {
    const float* probs  = (const float*)d_in[0];
    const float* logits = (const float*)d_in[1];
    const float* fm     = (const float*)d_in[2];
    float* out = (float*)d_out;

    char* ws = (char*)d_ws;
    uint32_t* bits   = (uint32_t*)(ws + OFF_BITS);
    uint32_t* hist   = (uint32_t*)(ws + OFF_HIST);
    uint32_t* ccnt   = (uint32_t*)(ws + OFF_CCNT);
    uint32_t* bstar  = (uint32_t*)(ws + OFF_BSTAR);
    unsigned long long* cand = (unsigned long long*)(ws + OFF_CAND);
    uint32_t* topk   = (uint32_t*)(ws + OFF_TOPK);

    // zero hist + candidate counters (ws is poisoned 0xAA before each launch)
    hipMemsetAsync((void*)hist, 0, SZ_HIST + SZ_CCNT, stream);

    int total = B_ * N_;
    int blk = 256;
    nms_hist_kernel<<<(total + blk - 1) / blk, blk, 0, stream>>>(probs, bits, hist);
    findbin_kernel<<<B_, 1024, 0, stream>>>(hist, bstar);
    collect_kernel<<<B_ * CBLK, 256, 0, stream>>>(bits, bstar, ccnt, cand);
    sort_kernel<<<B_, 1024, 0, stream>>>(cand, ccnt, topk);

    int waves = B_ * K_;                    // one wave per keypoint
    int threads = waves * 64;
    final_kernel<<<(threads + 255) / 256, 256, 0, stream>>>(topk, probs, logits, fm, out);
}

// Round 2
// 631.001 us; speedup vs baseline: 1.4220x; 1.0260x over previous
//
#include <hip/hip_runtime.h>
#include <stdint.h>

#define B_ 4
#define H_ 640
#define W_ 640
#define C_ 64
#define K_ 2048
#define N_ (H_ * W_)
#define NBINS 131072        // 2^17 bins of (bits >> 13)
#define CAP 4096            // candidate cap per batch (power of 2 for bitonic)
#define CBLK 64             // collect blocks per batch
#define CHUNK (N_ / CBLK)   // 6400 elements per collect block

// ---- workspace layout (bytes) ----
#define OFF_BITS   0
#define SZ_BITS    (B_ * N_ * 4)                 // 6,553,600
#define OFF_HIST   (OFF_BITS + SZ_BITS)          // 6,553,600
#define SZ_HIST    (B_ * NBINS * 4)              // 2,097,152
#define OFF_CCNT   (OFF_HIST + SZ_HIST)          // 8,650,752
#define SZ_CCNT    256                           // 4 counters padded to 64B lines
#define OFF_BSTAR  (OFF_CCNT + SZ_CCNT)          // 8,651,008
#define SZ_BSTAR   16
#define OFF_CAND   (OFF_BSTAR + SZ_BSTAR)        // 8,651,024 (16B aligned)
#define SZ_CAND    (B_ * CAP * 8)                // 131,072
#define OFF_TOPK   (OFF_CAND + SZ_CAND)
#define SZ_TOPK    (B_ * K_ * 4)

// Kernel 1: 3x3 NMS (-inf pad semantics) + histogram of nonzero value bits.
// float4-vectorized: each thread owns 4 consecutive pixels of one row.
__global__ void nms_hist_kernel(const float* __restrict__ p,
                                uint32_t* __restrict__ bits_out,
                                uint32_t* __restrict__ hist) {
    int t = blockIdx.x * blockDim.x + threadIdx.x;
    if (t >= B_ * N_ / 4) return;
    int b = t / (N_ / 4);
    int i4 = (t - b * (N_ / 4)) * 4;       // first pixel index (multiple of 4)
    int y = i4 / W_;
    int x0 = i4 - y * W_;                  // multiple of 4, W_ % 4 == 0
    const float* pb = p + (size_t)b * N_;

    float4 rows[3];
    float lft[3], rgt[3];
    #pragma unroll
    for (int r = 0; r < 3; r++) {
        int yy = y + r - 1;
        if (yy < 0 || yy >= H_) {
            rows[r] = make_float4(-1.f, -1.f, -1.f, -1.f);
            lft[r] = -1.f; rgt[r] = -1.f;
        } else {
            const float* rp = pb + yy * W_;
            rows[r] = *(const float4*)(rp + x0);          // 16B aligned
            lft[r] = (x0 > 0)       ? rp[x0 - 1] : -1.f;  // p >= 0: -1 acts as -inf
            rgt[r] = (x0 + 4 < W_)  ? rp[x0 + 4] : -1.f;
        }
    }
    float m0 = -1.f, m1 = -1.f, m2 = -1.f, m3 = -1.f;
    #pragma unroll
    for (int r = 0; r < 3; r++) {
        float4 v = rows[r];
        m0 = fmaxf(m0, fmaxf(fmaxf(lft[r], v.x), v.y));
        m1 = fmaxf(m1, fmaxf(fmaxf(v.x, v.y), v.z));
        m2 = fmaxf(m2, fmaxf(fmaxf(v.y, v.z), v.w));
        m3 = fmaxf(m3, fmaxf(fmaxf(v.z, v.w), rgt[r]));
    }
    float4 c = rows[1];
    uint4 bits;
    bits.x = (c.x == m0) ? __float_as_uint(c.x) : 0u;
    bits.y = (c.y == m1) ? __float_as_uint(c.y) : 0u;
    bits.z = (c.z == m2) ? __float_as_uint(c.z) : 0u;
    bits.w = (c.w == m3) ? __float_as_uint(c.w) : 0u;
    *(uint4*)(bits_out + (size_t)b * N_ + i4) = bits;

    uint32_t* hb = hist + b * NBINS;
    if (bits.x) atomicAdd(&hb[bits.x >> 13], 1u);
    if (bits.y) atomicAdd(&hb[bits.y >> 13], 1u);
    if (bits.z) atomicAdd(&hb[bits.z >> 13], 1u);
    if (bits.w) atomicAdd(&hb[bits.w >> 13], 1u);
}

// Kernel 2: per-batch, find bin b* s.t. count(bins >= b*) >= K > count(bins > b*)
// Fully-coalesced two-level scan. Phase A: 64 segment sums (2048 bins each),
// uint4 lane-contiguous loads. Phase B: wave-0 suffix scan -> segment. Phase C:
// segment -> LDS, chunk sums of 32 (rotated, conflict-free), suffix scans -> bin.
__global__ __launch_bounds__(1024) void findbin_kernel(const uint32_t* __restrict__ hist,
                                                       uint32_t* __restrict__ binstar) {
    int b = blockIdx.x;
    const uint32_t* h = hist + b * NBINS;
    __shared__ uint32_t segsum[64];
    __shared__ uint32_t seg[2048];
    __shared__ uint32_t s_sel, s_scum;
    int tid = threadIdx.x;
    int lane = tid & 63, wv = tid >> 6;

    // Phase A: wave wv sums segments [wv*4, wv*4+4)
    #pragma unroll
    for (int si = 0; si < 4; si++) {
        int s = wv * 4 + si;
        const uint32_t* sb = h + s * 2048;
        uint32_t acc = 0;
        #pragma unroll
        for (int it = 0; it < 8; it++) {
            uint4 v = *(const uint4*)(sb + (it * 64 + lane) * 4);   // coalesced 1KB/instr
            acc += v.x + v.y + v.z + v.w;
        }
        #pragma unroll
        for (int off = 32; off > 0; off >>= 1) acc += __shfl_down(acc, off);
        if (lane == 0) segsum[s] = acc;
    }
    __syncthreads();

    // Phase B: wave 0 selects the crossing segment
    if (wv == 0) {
        uint32_t own = segsum[lane];
        uint32_t inc = own;
        #pragma unroll
        for (int off = 1; off < 64; off <<= 1) {
            uint32_t v = __shfl_down(inc, off);
            if (lane + off < 64) inc += v;
        }
        uint32_t above = inc - own;                 // count in segments > lane
        bool sel = (above < (uint32_t)K_) && (inc >= (uint32_t)K_);
        unsigned long long msk = __ballot(sel);
        if (lane == 0) {
            if (msk == 0ULL) { s_sel = 0xFFFFFFFFu; }
            else {
                int s = __ffsll((long long)msk) - 1;
                s_sel = (uint32_t)s;
            }
        }
        if (msk != 0ULL) {
            int s = __ffsll((long long)msk) - 1;
            uint32_t sc = __shfl(above, s);
            if (lane == 0) s_scum = sc;
        }
    }
    __syncthreads();

    uint32_t selseg = s_sel;
    if (selseg == 0xFFFFFFFFu) {                    // fewer than K nonzero: take all
        if (tid == 0) binstar[b] = 0;
        return;
    }
    // copy selected segment (2048 bins) to LDS, coalesced uint4
    if (tid < 512) {
        ((uint4*)seg)[tid] = ((const uint4*)(h + selseg * 2048))[tid];
    }
    __syncthreads();

    // Phase C: wave 0 refines within the segment
    if (wv == 0) {
        uint32_t scum = s_scum;
        // chunk sums: chunk l = bins [l*32, l*32+32); rotated -> conflict-free
        uint32_t cs = 0;
        #pragma unroll
        for (int j = 0; j < 32; j++) cs += seg[lane * 32 + ((j + lane) & 31)];
        uint32_t incc = cs;
        #pragma unroll
        for (int off = 1; off < 64; off <<= 1) {
            uint32_t v = __shfl_down(incc, off);
            if (lane + off < 64) incc += v;
        }
        uint32_t above2 = scum + (incc - cs);       // count above chunk
        bool sel2 = (above2 < (uint32_t)K_) && (above2 + cs >= (uint32_t)K_);
        unsigned long long m2 = __ballot(sel2);
        int cidx = __ffsll((long long)m2) - 1;      // uniform
        uint32_t scum2 = __shfl(above2, cidx);
        // final 32 bins
        uint32_t bv = (lane < 32) ? seg[cidx * 32 + lane] : 0u;
        uint32_t incb = bv;
        #pragma unroll
        for (int off = 1; off < 32; off <<= 1) {
            uint32_t v = __shfl_down(incb, off);
            if (lane + off < 32) incb += v;
        }
        uint32_t above3 = scum2 + (incb - bv);
        if (lane < 32 && above3 < (uint32_t)K_ && above3 + bv >= (uint32_t)K_) {
            binstar[b] = (uint32_t)(selseg * 2048 + cidx * 32 + lane);
        }
    }
}

// Kernel 3: collect candidate keys (value bits desc, index asc tie-break).
// Two-phase block aggregation: ONE atomic per block (padded counters).
__global__ __launch_bounds__(256) void collect_kernel(const uint32_t* __restrict__ bits_in,
                                                      const uint32_t* __restrict__ binstar,
                                                      uint32_t* __restrict__ ccnt,
                                                      unsigned long long* __restrict__ cand) {
    int b = blockIdx.x / CBLK;
    int c = blockIdx.x - b * CBLK;
    int base = b * N_ + c * CHUNK;
    uint32_t bstar = binstar[b];
    int tid = threadIdx.x;
    int lane = tid & 63, wv = tid >> 6;
    __shared__ uint32_t wtot[4];
    __shared__ uint32_t blkbase;

    // phase 1: count passers in this block's chunk
    uint32_t cnt = 0;
    for (int j = tid; j < CHUNK; j += 256) {
        uint32_t bits = bits_in[base + j];
        if (bits && (bits >> 13) >= bstar) cnt++;
    }
    #pragma unroll
    for (int off = 32; off > 0; off >>= 1) cnt += __shfl_down(cnt, off);
    if (lane == 0) wtot[wv] = cnt;
    __syncthreads();
    if (tid == 0) {
        uint32_t tot = wtot[0] + wtot[1] + wtot[2] + wtot[3];
        blkbase = tot ? atomicAdd(&ccnt[b * 16], tot) : 0u;
    }
    __syncthreads();
    uint32_t wbase = blkbase;
    #pragma unroll
    for (int w2 = 0; w2 < 4; w2++) if (w2 < wv) wbase += wtot[w2];

    // phase 2: deterministic intra-wave placement via ballot prefix
    uint32_t run = 0;
    for (int j = tid; j < CHUNK; j += 256) {   // CHUNK % 256 == 0: no ragged tail
        uint32_t bits = bits_in[base + j];
        bool pass = bits && (bits >> 13) >= bstar;
        unsigned long long mask = __ballot(pass);
        if (pass) {
            uint32_t pos = wbase + run + (uint32_t)__popcll(mask & ((1ull << lane) - 1));
            int i = c * CHUNK + j;
            if (pos < CAP)
                cand[(size_t)b * CAP + pos] =
                    ((unsigned long long)bits << 32) | (unsigned long long)(0xFFFFFFFFu - (uint32_t)i);
        }
        run += (uint32_t)__popcll(mask);
    }
}

// Kernel 4: per-batch bitonic sort (descending) of <= CAP keys, emit top-K indices
__global__ __launch_bounds__(1024) void sort_kernel(const unsigned long long* __restrict__ cand,
                                                    const uint32_t* __restrict__ ccnt,
                                                    uint32_t* __restrict__ topk) {
    __shared__ unsigned long long sh[CAP];   // 32 KB
    int b = blockIdx.x;
    int tid = threadIdx.x;
    uint32_t cnt = ccnt[b * 16];
    if (cnt > CAP) cnt = CAP;
    const unsigned long long* cb = cand + (size_t)b * CAP;
    for (int j = tid; j < CAP; j += 1024) sh[j] = (j < (int)cnt) ? cb[j] : 0ULL;
    __syncthreads();
    for (unsigned k = 2; k <= CAP; k <<= 1) {
        for (unsigned j = k >> 1; j > 0; j >>= 1) {
            for (unsigned t = tid; t < CAP / 2; t += 1024) {
                unsigned i = (t / j) * (2 * j) + (t % j);
                unsigned ixj = i + j;
                unsigned long long a = sh[i], cc = sh[ixj];
                bool dirDesc = ((i & k) == 0);
                if (dirDesc ? (a < cc) : (a > cc)) { sh[i] = cc; sh[ixj] = a; }
            }
            __syncthreads();
        }
    }
    for (int k2 = tid; k2 < K_; k2 += 1024) {
        topk[b * K_ + k2] = 0xFFFFFFFFu - (uint32_t)(sh[k2] & 0xFFFFFFFFull);
    }
}

// Kernel 5: one wave (64 lanes) per keypoint: subpixel softmax refine + bilinear sample
__global__ void final_kernel(const uint32_t* __restrict__ topk,
                             const float* __restrict__ probs,
                             const float* __restrict__ logits,
                             const float* __restrict__ fm,
                             float* __restrict__ out) {
    int gtid = blockIdx.x * blockDim.x + threadIdx.x;
    int wid = gtid >> 6;          // one wave per keypoint
    int lane = threadIdx.x & 63;
    if (wid >= B_ * K_) return;
    int b = wid / K_;
    int k = wid - b * K_;
    int idx = (int)topk[b * K_ + k];
    int h = idx / W_;
    int w = idx - h * W_;

    // 3x3 logit patch, zero-padded borders, temp 0.5 softmax
    const float* lg = logits + (size_t)b * N_;
    float v[9];
    #pragma unroll
    for (int di = 0; di < 3; di++) {
        #pragma unroll
        for (int dj = 0; dj < 3; dj++) {
            int yy = h + di - 1, xx = w + dj - 1;
            float val = (yy >= 0 && yy < H_ && xx >= 0 && xx < W_) ? lg[yy * W_ + xx] : 0.0f;
            v[di * 3 + dj] = val * 2.0f;   // / SUBPIXEL_TEMP
        }
    }
    float m = v[0];
    #pragma unroll
    for (int j = 1; j < 9; j++) m = fmaxf(m, v[j]);
    float e[9], s = 0.0f;
    #pragma unroll
    for (int j = 0; j < 9; j++) { e[j] = __expf(v[j] - m); s += e[j]; }
    float inv = 1.0f / s;
    float dx = 0.0f, dy = 0.0f;
    #pragma unroll
    for (int di = 0; di < 3; di++) {
        #pragma unroll
        for (int dj = 0; dj < 3; dj++) {
            float pr = e[di * 3 + dj] * inv;
            dx += pr * (float)(dj - 1);
            dy += pr * (float)(di - 1);
        }
    }
    float x = (float)w + dx;
    float y = (float)h + dy;

    // bilinear sample coords (clipped)
    float xc = fminf(fmaxf(x, 0.0f), (float)(W_ - 1));
    float yc = fminf(fmaxf(y, 0.0f), (float)(H_ - 1));
    float x0f = floorf(xc), y0f = floorf(yc);
    float wx = xc - x0f, wy = yc - y0f;
    int x0 = (int)x0f, y0 = (int)y0f;
    int x1 = min(x0 + 1, W_ - 1), y1 = min(y0 + 1, H_ - 1);
    float w00 = (1.0f - wx) * (1.0f - wy);
    float w01 = wx * (1.0f - wy);
    float w10 = (1.0f - wx) * wy;
    float w11 = wx * wy;
    int i00 = y0 * W_ + x0, i01 = y0 * W_ + x1, i10 = y1 * W_ + x0, i11 = y1 * W_ + x1;

    float* ob = out + ((size_t)b * K_ + k) * (C_ + 3);

    // lane l samples feature channel l
    const float* ch = fm + ((size_t)b * C_ + lane) * N_;
    float sv = ch[i00] * w00 + ch[i01] * w01 + ch[i10] * w10 + ch[i11] * w11;
    ob[3 + lane] = sv;

    if (lane == 0) {
        const float* pp = probs + (size_t)b * N_;
        float sp = pp[i00] * w00 + pp[i01] * w01 + pp[i10] * w10 + pp[i11] * w11;
        ob[0] = x;
        ob[1] = y;
        ob[2] = sp;
    }
}

extern "C" void kernel_launch(void* const* d_in, const int* in_sizes, int n_in,
                              void* d_out, int out_size, void* d_ws, size_t ws_size,
                              hipStream_t stream) {
    const float* probs  = (const float*)d_in[0];
    const float* logits = (const float*)d_in[1];
    const float* fm     = (const float*)d_in[2];
    float* out = (float*)d_out;

    char* ws = (char*)d_ws;
    uint32_t* bits   = (uint32_t*)(ws + OFF_BITS);
    uint32_t* hist   = (uint32_t*)(ws + OFF_HIST);
    uint32_t* ccnt   = (uint32_t*)(ws + OFF_CCNT);
    uint32_t* bstar  = (uint32_t*)(ws + OFF_BSTAR);
    unsigned long long* cand = (unsigned long long*)(ws + OFF_CAND);
    uint32_t* topk   = (uint32_t*)(ws + OFF_TOPK);

    // zero hist + candidate counters (ws is poisoned 0xAA before each launch)
    hipMemsetAsync((void*)hist, 0, SZ_HIST + SZ_CCNT, stream);

    int blk = 256;
    int total4 = B_ * N_ / 4;
    nms_hist_kernel<<<(total4 + blk - 1) / blk, blk, 0, stream>>>(probs, bits, hist);
    findbin_kernel<<<B_, 1024, 0, stream>>>(hist, bstar);
    collect_kernel<<<B_ * CBLK, 256, 0, stream>>>(bits, bstar, ccnt, cand);
    sort_kernel<<<B_, 1024, 0, stream>>>(cand, ccnt, topk);

    int waves = B_ * K_;                    // one wave per keypoint
    int threads = waves * 64;
    final_kernel<<<(threads + 255) / 256, 256, 0, stream>>>(topk, probs, logits, fm, out);
}